// Round 5
// baseline (425.858 us; speedup 1.0000x reference)
//
#include <hip/hip_runtime.h>
#include <hip/hip_fp16.h>

#define N_NODES 50000
#define N_EDGES 1000000
#define D 64
#define L 3
#define BN_EPS 1e-5f
#define NB_SCAN ((N_NODES + 255) / 256)  // 196 blocks of 256

// ---------------------------------------------------------------- helpers
__device__ inline void bn_affine(const float* __restrict__ bnsum,
                                 const float* __restrict__ gamma,
                                 const float* __restrict__ beta,
                                 int c, float& sc, float& sh) {
    float mean = bnsum[c] * (1.f / N_NODES);
    float var = fmaf(-mean, mean, bnsum[D + c] * (1.f / N_NODES));
    float inv = rsqrtf(var + BN_EPS);
    sc = gamma[c] * inv;
    sh = fmaf(-mean, sc, beta[c]);
}

__device__ inline float unpack_w(unsigned int m) {
    __half_raw hr;
    hr.x = (unsigned short)(m & 0xffffu);
    __half h = *reinterpret_cast<__half*>(&hr);
    return __half2float(h);
}

__device__ inline float2 unpack_x2(unsigned int q) {
    __half2 h2 = *reinterpret_cast<__half2*>(&q);
    return __half22float2(h2);
}

__device__ inline float2 ntload_f2(const float2* p) {
    unsigned long long u = __builtin_nontemporal_load((const unsigned long long*)p);
    float2 r;
    r.x = __uint_as_float((unsigned int)(u & 0xffffffffull));
    r.y = __uint_as_float((unsigned int)(u >> 32));
    return r;
}

__device__ inline void ntstore_f2(float2* p, float2 v) {
    unsigned long long u =
        ((unsigned long long)__float_as_uint(v.y) << 32) | (unsigned long long)__float_as_uint(v.x);
    __builtin_nontemporal_store(u, (unsigned long long*)p);
}

// ---------------------------------------------------------------- init
__global__ void init_kernel(int* __restrict__ counts, float* __restrict__ bnsum) {
    int i = blockIdx.x * blockDim.x + threadIdx.x;
    int stride = gridDim.x * blockDim.x;
    for (int j = i; j < N_NODES; j += stride) counts[j] = 0;
    for (int j = i; j < L * 2 * D; j += stride) bnsum[j] = 0.f;
}

// ---------------------------------------------------------------- CSR build
__global__ void count_kernel(const int* __restrict__ dst, int* __restrict__ counts,
                             unsigned short* __restrict__ rank) {
    int i = blockIdx.x * blockDim.x + threadIdx.x;
    int stride = gridDim.x * blockDim.x;
    for (int e = i; e < N_EDGES; e += stride) {
        int r = atomicAdd(&counts[dst[e]], 1);
        rank[e] = (unsigned short)r;
    }
}

__global__ __launch_bounds__(256) void scanA_kernel(const int* __restrict__ counts,
                                                    int* __restrict__ blocksum) {
    __shared__ int buf[256];
    int t = threadIdx.x, b = blockIdx.x;
    int i = b * 256 + t;
    int v = (i < N_NODES) ? counts[i] : 0;
    buf[t] = v;
    __syncthreads();
    for (int off = 128; off > 0; off >>= 1) {
        if (t < off) buf[t] += buf[t + off];
        __syncthreads();
    }
    if (t == 0) blocksum[b] = buf[0];
}

__global__ __launch_bounds__(256) void scanB_kernel(const int* __restrict__ blocksum,
                                                    int* __restrict__ blockoff,
                                                    int* __restrict__ row_ptr) {
    __shared__ int buf[256];
    int t = threadIdx.x;
    int v = (t < NB_SCAN) ? blocksum[t] : 0;
    buf[t] = v;
    __syncthreads();
    for (int off = 1; off < 256; off <<= 1) {
        int u = (t >= off) ? buf[t - off] : 0;
        __syncthreads();
        buf[t] += u;
        __syncthreads();
    }
    if (t < NB_SCAN) blockoff[t] = buf[t] - v;  // exclusive
    if (t == NB_SCAN - 1) row_ptr[N_NODES] = buf[t];
}

__global__ __launch_bounds__(256) void scanC_kernel(const int* __restrict__ counts,
                                                    const int* __restrict__ blockoff,
                                                    int* __restrict__ row_ptr) {
    __shared__ int buf[256];
    int t = threadIdx.x, b = blockIdx.x;
    int i = b * 256 + t;
    int v = (i < N_NODES) ? counts[i] : 0;
    buf[t] = v;
    __syncthreads();
    for (int off = 1; off < 256; off <<= 1) {
        int u = (t >= off) ? buf[t - off] : 0;
        __syncthreads();
        buf[t] += u;
        __syncthreads();
    }
    if (i < N_NODES) row_ptr[i] = blockoff[b] + buf[t] - v;
}

// scatter edges into dst-sorted order; no atomics (rank precomputed)
__global__ void fill_kernel(const int* __restrict__ src, const int* __restrict__ dst,
                            const float* __restrict__ w,
                            const unsigned short* __restrict__ rank,
                            const int* __restrict__ row_ptr,
                            unsigned int* __restrict__ em) {
    int i = blockIdx.x * blockDim.x + threadIdx.x;
    int stride = gridDim.x * blockDim.x;
    for (int e = i; e < N_EDGES; e += stride) {
        int d = dst[e];
        int p = row_ptr[d] + (int)rank[e];
        __half h = __float2half_rn(w[e]);
        unsigned short wb = reinterpret_cast<__half_raw*>(&h)->x;
        em[p] = ((unsigned int)src[e] << 16) | (unsigned int)wb;
    }
}

// ---------------------------------------------------------------- GEMM
// xw2 layout: [2][N][32] fp16 (two 3.2 MB feature-halves).
__global__ __launch_bounds__(256) void gemm_kernel(const float* __restrict__ hraw,
                                                   const float* __restrict__ bnsum_p,
                                                   const float* __restrict__ gamma_p,
                                                   const float* __restrict__ beta_p,
                                                   const float* __restrict__ Wl,
                                                   __half* __restrict__ xw2) {
    __shared__ float aff[2][D];
    int tid = threadIdx.x, lane = tid & 63, wave = tid >> 6;
    if (tid < D) {
        float sc = 1.f, sh = 0.f;
        if (bnsum_p) bn_affine(bnsum_p, gamma_p, beta_p, tid, sc, sh);
        aff[0][tid] = sc;
        aff[1][tid] = sh;
    }
    __syncthreads();
    float Wreg[D];
    float biasc = 0.f;
#pragma unroll
    for (int k = 0; k < D; k++) {
        float wkc = Wl[k * D + lane];
        biasc = fmaf(aff[1][k], wkc, biasc);
        Wreg[k] = wkc * aff[0][k];
    }
    int halfid = lane >> 5, fl2 = lane & 31;
    __half* dstp = xw2 + (size_t)halfid * N_NODES * 32;
    int gw = blockIdx.x * 4 + wave, nw = gridDim.x * 4;
    for (int v = gw; v < N_NODES; v += nw) {
        const float* hp = hraw + (size_t)__builtin_amdgcn_readfirstlane(v) * D;
        float acc = biasc;
#pragma unroll
        for (int k = 0; k < D; k++) acc = fmaf(hp[k], Wreg[k], acc);
        dstp[v * 32 + fl2] = __float2half_rn(acc);
    }
}

// ---------------------------------------------------------------- aggregate
// One pass covers features [32*FH, 32*FH+32). Quarter-wave (16 lanes) per edge:
// grp = lane>>4 handles edge e+grp; fl = lane&15 handles feature-pair {2fl,2fl+1}.
// xwh = this pass's half, [N][16] uints (half2). em/residual/hpre go nontemporal
// so L2 stays reserved for the 3.2 MB xwh gather.
__global__ __launch_bounds__(256) void agg_kernel(const unsigned int* __restrict__ xwh,
                                                  const int* __restrict__ row_ptr,
                                                  const unsigned int* __restrict__ em,
                                                  const float* __restrict__ bl,
                                                  const float* __restrict__ pa,
                                                  const float* __restrict__ hraw_prev,
                                                  const float* __restrict__ bnsum_p,
                                                  const float* __restrict__ gamma_p,
                                                  const float* __restrict__ beta_p,
                                                  float* __restrict__ hpre,
                                                  float* __restrict__ bnsum,
                                                  int FH) {
    int tid = threadIdx.x, lane = tid & 63, wave = tid >> 6;
    int grp = lane >> 4, fl = lane & 15;
    int gw = blockIdx.x * 4 + wave, nw = gridDim.x * 4;
    float al = pa[0];
    int c0 = FH * 32 + 2 * fl;
    float2 bias = ((const float2*)bl)[FH * 16 + fl];
    float sc0 = 0.f, sh0 = 0.f, sc1 = 0.f, sh1 = 0.f;
    if (hraw_prev) {
        bn_affine(bnsum_p, gamma_p, beta_p, c0, sc0, sh0);
        bn_affine(bnsum_p, gamma_p, beta_p, c0 + 1, sc1, sh1);
    }
    float s1x = 0.f, s1y = 0.f, s2x = 0.f, s2y = 0.f;
    for (int v = gw; v < N_NODES; v += nw) {
        int e0 = row_ptr[v], e1 = row_ptr[v + 1];
        float ax0 = 0.f, ay0 = 0.f, ax1 = 0.f, ay1 = 0.f;
        int e = e0;
        for (; e + 16 <= e1; e += 16) {
            unsigned int m0 = __builtin_nontemporal_load(em + e + 0 + grp);
            unsigned int m1 = __builtin_nontemporal_load(em + e + 4 + grp);
            unsigned int m2 = __builtin_nontemporal_load(em + e + 8 + grp);
            unsigned int m3 = __builtin_nontemporal_load(em + e + 12 + grp);
            unsigned int q0 = xwh[(m0 >> 16) * 16 + fl];
            unsigned int q1 = xwh[(m1 >> 16) * 16 + fl];
            unsigned int q2 = xwh[(m2 >> 16) * 16 + fl];
            unsigned int q3 = xwh[(m3 >> 16) * 16 + fl];
            float w0 = unpack_w(m0), w1 = unpack_w(m1), w2 = unpack_w(m2), w3 = unpack_w(m3);
            float2 f0 = unpack_x2(q0), f1 = unpack_x2(q1), f2 = unpack_x2(q2), f3 = unpack_x2(q3);
            ax0 = fmaf(w0, f0.x, ax0); ay0 = fmaf(w0, f0.y, ay0);
            ax1 = fmaf(w1, f1.x, ax1); ay1 = fmaf(w1, f1.y, ay1);
            ax0 = fmaf(w2, f2.x, ax0); ay0 = fmaf(w2, f2.y, ay0);
            ax1 = fmaf(w3, f3.x, ax1); ay1 = fmaf(w3, f3.y, ay1);
        }
        for (; e < e1; e += 4) {
            int idx = e + grp;
            if (idx < e1) {
                unsigned int m = __builtin_nontemporal_load(em + idx);
                unsigned int q = xwh[(m >> 16) * 16 + fl];
                float wv = unpack_w(m);
                float2 f = unpack_x2(q);
                ax0 = fmaf(wv, f.x, ax0);
                ay0 = fmaf(wv, f.y, ay0);
            }
        }
        float ax = ax0 + ax1, ay = ay0 + ay1;
        ax += __shfl_xor(ax, 16, 64);
        ax += __shfl_xor(ax, 32, 64);
        ay += __shfl_xor(ay, 16, 64);
        ay += __shfl_xor(ay, 32, 64);
        if (grp == 0) {
            ax += bias.x;
            ay += bias.y;
            float hx = ax >= 0.f ? ax : al * ax;
            float hy = ay >= 0.f ? ay : al * ay;
            int ridx = v * 32 + FH * 16 + fl;
            if (hraw_prev) {
                float2 hp = ntload_f2((const float2*)hraw_prev + ridx);
                hx = fmaf(hp.x, sc0, hx + sh0);
                hy = fmaf(hp.y, sc1, hy + sh1);
            }
            ntstore_f2((float2*)hpre + ridx, make_float2(hx, hy));
            s1x += hx; s1y += hy;
            s2x = fmaf(hx, hx, s2x);
            s2y = fmaf(hy, hy, s2y);
        }
    }
    __shared__ float red[8][32];
    if (lane < 16) {
        red[wave][2 * fl] = s1x;
        red[wave][2 * fl + 1] = s1y;
        red[4 + wave][2 * fl] = s2x;
        red[4 + wave][2 * fl + 1] = s2y;
    }
    __syncthreads();
    if (wave == 0 && lane < 32) {
        float t1 = red[0][lane] + red[1][lane] + red[2][lane] + red[3][lane];
        float t2 = red[4][lane] + red[5][lane] + red[6][lane] + red[7][lane];
        atomicAdd(&bnsum[FH * 32 + lane], t1);
        atomicAdd(&bnsum[D + FH * 32 + lane], t2);
    }
}

// ---------------------------------------------------------------- final BN apply
__global__ __launch_bounds__(256) void bnapply_kernel(const float* __restrict__ hpre,
                                                      const float* __restrict__ bnsum_p,
                                                      const float* __restrict__ gamma_p,
                                                      const float* __restrict__ beta_p,
                                                      float* __restrict__ out) {
    __shared__ float aff[2][D];
    int tid = threadIdx.x;
    if (tid < D) {
        float sc, sh;
        bn_affine(bnsum_p, gamma_p, beta_p, tid, sc, sh);
        aff[0][tid] = sc;
        aff[1][tid] = sh;
    }
    __syncthreads();
    int i = blockIdx.x * blockDim.x + tid;
    int stride = gridDim.x * blockDim.x;
    const int NQ = N_NODES * D / 4;
    for (int j = i; j < NQ; j += stride) {
        float4 hv = ((const float4*)hpre)[j];
        int c = (j * 4) & 63;
        float4 o;
        o.x = fmaf(hv.x, aff[0][c + 0], aff[1][c + 0]);
        o.y = fmaf(hv.y, aff[0][c + 1], aff[1][c + 1]);
        o.z = fmaf(hv.z, aff[0][c + 2], aff[1][c + 2]);
        o.w = fmaf(hv.w, aff[0][c + 3], aff[1][c + 3]);
        ((float4*)out)[j] = o;
    }
}

// ---------------------------------------------------------------- launch
extern "C" void kernel_launch(void* const* d_in, const int* in_sizes, int n_in,
                              void* d_out, int out_size, void* d_ws, size_t ws_size,
                              hipStream_t stream) {
    const float* x     = (const float*)d_in[0];
    const int*   esrc  = (const int*)d_in[1];
    const int*   edst  = (const int*)d_in[2];
    const float* ew    = (const float*)d_in[3];
    const float* W     = (const float*)d_in[4];
    const float* b     = (const float*)d_in[5];
    const float* pa    = (const float*)d_in[6];
    const float* gamma = (const float*)d_in[7];
    const float* beta  = (const float*)d_in[8];
    float* out = (float*)d_out;

    char* ws = (char*)d_ws;
    size_t off = 0;
    auto alloc = [&](size_t bytes) -> char* {
        char* p = ws + off;
        off = (off + bytes + 255) & ~(size_t)255;
        return p;
    };
    int*            counts   = (int*)alloc((size_t)N_NODES * 4);
    int*            row_ptr  = (int*)alloc((size_t)(N_NODES + 1) * 4);
    int*            blocksum = (int*)alloc((size_t)NB_SCAN * 4);
    int*            blockoff = (int*)alloc((size_t)NB_SCAN * 4);
    unsigned short* rank     = (unsigned short*)alloc((size_t)N_EDGES * 2);
    unsigned int*   em       = (unsigned int*)alloc((size_t)N_EDGES * 4);
    __half*         xw2      = (__half*)alloc((size_t)2 * N_NODES * 32 * 2);
    float*          hpre1    = (float*)alloc((size_t)N_NODES * D * 4);
    float*          bnsum    = (float*)alloc((size_t)L * 2 * D * 4);

    init_kernel<<<256, 256, 0, stream>>>(counts, bnsum);
    count_kernel<<<2048, 256, 0, stream>>>(edst, counts, rank);
    scanA_kernel<<<NB_SCAN, 256, 0, stream>>>(counts, blocksum);
    scanB_kernel<<<1, 256, 0, stream>>>(blocksum, blockoff, row_ptr);
    scanC_kernel<<<NB_SCAN, 256, 0, stream>>>(counts, blockoff, row_ptr);
    fill_kernel<<<2048, 256, 0, stream>>>(esrc, edst, ew, rank, row_ptr, em);

    // hpre storage: layer0 -> d_out, layer1 -> ws, layer2 -> d_out
    float* hbuf[L] = {out, hpre1, out};
    for (int i = 0; i < L; i++) {
        const float* hin = (i == 0) ? x : hbuf[i - 1];
        const float* bns = (i == 0) ? nullptr : bnsum + (i - 1) * 2 * D;
        const float* gmp = (i == 0) ? nullptr : gamma + (i - 1) * D;
        const float* btp = (i == 0) ? nullptr : beta + (i - 1) * D;
        gemm_kernel<<<512, 256, 0, stream>>>(hin, bns, gmp, btp, W + (size_t)i * D * D, xw2);
        // Two serialized passes, each gathering from one 3.2 MB xw half (L2-resident).
        for (int FH = 0; FH < 2; FH++) {
            const unsigned int* xwh = (const unsigned int*)xw2 + (size_t)FH * N_NODES * 16;
            agg_kernel<<<2048, 256, 0, stream>>>(xwh, row_ptr, em, b + i * D, pa + i,
                                                 (i == 0) ? nullptr : hbuf[i - 1],
                                                 bns, gmp, btp,
                                                 hbuf[i], bnsum + i * 2 * D, FH);
        }
    }
    bnapply_kernel<<<2048, 256, 0, stream>>>(hbuf[2], bnsum + 2 * 2 * D,
                                             gamma + 2 * D, beta + 2 * D, out);
}

// Round 6
// 278.259 us; speedup vs baseline: 1.5304x; 1.5304x over previous
//
#include <hip/hip_runtime.h>
#include <hip/hip_fp16.h>

#define N_NODES 50000
#define N_EDGES 1000000
#define D 64
#define L 3
#define BN_EPS 1e-5f
#define NB_SCAN ((N_NODES + 255) / 256)  // 196 blocks of 256
#define AGG_BLOCKS 1024

// ---------------------------------------------------------------- helpers
__device__ inline void bn_affine(const float* __restrict__ bnsum,
                                 const float* __restrict__ gamma,
                                 const float* __restrict__ beta,
                                 int c, float& sc, float& sh) {
    float mean = bnsum[c] * (1.f / N_NODES);
    float var = fmaf(-mean, mean, bnsum[D + c] * (1.f / N_NODES));
    float inv = rsqrtf(var + BN_EPS);
    sc = gamma[c] * inv;
    sh = fmaf(-mean, sc, beta[c]);
}

__device__ inline float unpack_w(unsigned int m) {
    __half_raw hr;
    hr.x = (unsigned short)(m & 0xffffu);
    __half h = *reinterpret_cast<__half*>(&hr);
    return __half2float(h);
}

__device__ inline float2 unpack_x2(unsigned int q) {
    __half2 h2 = *reinterpret_cast<__half2*>(&q);
    return __half22float2(h2);
}

__device__ inline float2 ntload_f2(const float2* p) {
    unsigned long long u = __builtin_nontemporal_load((const unsigned long long*)p);
    float2 r;
    r.x = __uint_as_float((unsigned int)(u & 0xffffffffull));
    r.y = __uint_as_float((unsigned int)(u >> 32));
    return r;
}

__device__ inline void ntstore_f2(float2* p, float2 v) {
    unsigned long long u =
        ((unsigned long long)__float_as_uint(v.y) << 32) | (unsigned long long)__float_as_uint(v.x);
    __builtin_nontemporal_store(u, (unsigned long long*)p);
}

// ---------------------------------------------------------------- init
__global__ void init_kernel(int* __restrict__ counts, float* __restrict__ bnsum) {
    int i = blockIdx.x * blockDim.x + threadIdx.x;
    int stride = gridDim.x * blockDim.x;
    for (int j = i; j < N_NODES; j += stride) counts[j] = 0;
    for (int j = i; j < L * 2 * D; j += stride) bnsum[j] = 0.f;
}

// ---------------------------------------------------------------- CSR build
__global__ void count_kernel(const int* __restrict__ dst, int* __restrict__ counts,
                             unsigned short* __restrict__ rank) {
    int i = blockIdx.x * blockDim.x + threadIdx.x;
    int stride = gridDim.x * blockDim.x;
    for (int e = i; e < N_EDGES; e += stride) {
        int r = atomicAdd(&counts[dst[e]], 1);
        rank[e] = (unsigned short)r;
    }
}

__global__ __launch_bounds__(256) void scanA_kernel(const int* __restrict__ counts,
                                                    int* __restrict__ blocksum) {
    __shared__ int buf[256];
    int t = threadIdx.x, b = blockIdx.x;
    int i = b * 256 + t;
    int v = (i < N_NODES) ? counts[i] : 0;
    buf[t] = v;
    __syncthreads();
    for (int off = 128; off > 0; off >>= 1) {
        if (t < off) buf[t] += buf[t + off];
        __syncthreads();
    }
    if (t == 0) blocksum[b] = buf[0];
}

__global__ __launch_bounds__(256) void scanB_kernel(const int* __restrict__ blocksum,
                                                    int* __restrict__ blockoff,
                                                    int* __restrict__ row_ptr) {
    __shared__ int buf[256];
    int t = threadIdx.x;
    int v = (t < NB_SCAN) ? blocksum[t] : 0;
    buf[t] = v;
    __syncthreads();
    for (int off = 1; off < 256; off <<= 1) {
        int u = (t >= off) ? buf[t - off] : 0;
        __syncthreads();
        buf[t] += u;
        __syncthreads();
    }
    if (t < NB_SCAN) blockoff[t] = buf[t] - v;  // exclusive
    if (t == NB_SCAN - 1) row_ptr[N_NODES] = buf[t];
}

__global__ __launch_bounds__(256) void scanC_kernel(const int* __restrict__ counts,
                                                    const int* __restrict__ blockoff,
                                                    int* __restrict__ row_ptr) {
    __shared__ int buf[256];
    int t = threadIdx.x, b = blockIdx.x;
    int i = b * 256 + t;
    int v = (i < N_NODES) ? counts[i] : 0;
    buf[t] = v;
    __syncthreads();
    for (int off = 1; off < 256; off <<= 1) {
        int u = (t >= off) ? buf[t - off] : 0;
        __syncthreads();
        buf[t] += u;
        __syncthreads();
    }
    if (i < N_NODES) row_ptr[i] = blockoff[b] + buf[t] - v;
}

// scatter edges into dst-sorted order; no atomics (rank precomputed)
__global__ void fill_kernel(const int* __restrict__ src, const int* __restrict__ dst,
                            const float* __restrict__ w,
                            const unsigned short* __restrict__ rank,
                            const int* __restrict__ row_ptr,
                            unsigned int* __restrict__ em) {
    int i = blockIdx.x * blockDim.x + threadIdx.x;
    int stride = gridDim.x * blockDim.x;
    for (int e = i; e < N_EDGES; e += stride) {
        int d = dst[e];
        int p = row_ptr[d] + (int)rank[e];
        __half h = __float2half_rn(w[e]);
        unsigned short wb = reinterpret_cast<__half_raw*>(&h)->x;
        em[p] = ((unsigned int)src[e] << 16) | (unsigned int)wb;
    }
}

// ---------------------------------------------------------------- GEMM
// xw[v][c] = sum_k (hraw[v][k]*scale[k]+shift[k]) * W[k][c], output fp16 [N][64].
__global__ __launch_bounds__(256) void gemm_kernel(const float* __restrict__ hraw,
                                                   const float* __restrict__ bnsum_p,
                                                   const float* __restrict__ gamma_p,
                                                   const float* __restrict__ beta_p,
                                                   const float* __restrict__ Wl,
                                                   __half* __restrict__ xw) {
    __shared__ float aff[2][D];
    int tid = threadIdx.x, lane = tid & 63, wave = tid >> 6;
    if (tid < D) {
        float sc = 1.f, sh = 0.f;
        if (bnsum_p) bn_affine(bnsum_p, gamma_p, beta_p, tid, sc, sh);
        aff[0][tid] = sc;
        aff[1][tid] = sh;
    }
    __syncthreads();
    float Wreg[D];
    float biasc = 0.f;
#pragma unroll
    for (int k = 0; k < D; k++) {
        float wkc = Wl[k * D + lane];
        biasc = fmaf(aff[1][k], wkc, biasc);
        Wreg[k] = wkc * aff[0][k];
    }
    int gw = blockIdx.x * 4 + wave, nw = gridDim.x * 4;
    for (int v = gw; v < N_NODES; v += nw) {
        const float* hp = hraw + (size_t)__builtin_amdgcn_readfirstlane(v) * D;
        float acc = biasc;
#pragma unroll
        for (int k = 0; k < D; k++) acc = fmaf(hp[k], Wreg[k], acc);
        xw[v * D + lane] = __float2half_rn(acc);
    }
}

// ---------------------------------------------------------------- aggregate
// One 16-lane group per node (16 nodes per block-batch). Lane fl owns features
// 4fl..4fl+3 for its node; each edge = ONE uint2 (8B) gather, 16 independent
// gathers per unrolled iter, tail predicated (w=0). No cross-lane reduction.
__global__ __launch_bounds__(256) void agg_kernel(const uint2* __restrict__ xw,
                                                  const int* __restrict__ row_ptr,
                                                  const unsigned int* __restrict__ em,
                                                  const float* __restrict__ bl,
                                                  const float* __restrict__ pa,
                                                  const float* __restrict__ hraw_prev,
                                                  const float* __restrict__ bnsum_p,
                                                  const float* __restrict__ gamma_p,
                                                  const float* __restrict__ beta_p,
                                                  float* __restrict__ hpre,
                                                  float* __restrict__ bnsum) {
    __shared__ float r1[D], r2[D];
    int tid = threadIdx.x, lane = tid & 63;
    int sub = tid >> 4;        // 0..15 : node slot within the block-batch
    int fl = lane & 15;        // feature-quad index
    int srcbase = lane & 48;   // group base lane for shfl
    if (tid < D) { r1[tid] = 0.f; r2[tid] = 0.f; }
    __syncthreads();

    float al = pa[0];
    int c0 = 4 * fl;
    float4 bias = ((const float4*)bl)[fl];
    float sc0 = 0, sc1 = 0, sc2 = 0, sc3 = 0, sh0 = 0, sh1 = 0, sh2 = 0, sh3 = 0;
    if (hraw_prev) {
        bn_affine(bnsum_p, gamma_p, beta_p, c0 + 0, sc0, sh0);
        bn_affine(bnsum_p, gamma_p, beta_p, c0 + 1, sc1, sh1);
        bn_affine(bnsum_p, gamma_p, beta_p, c0 + 2, sc2, sh2);
        bn_affine(bnsum_p, gamma_p, beta_p, c0 + 3, sc3, sh3);
    }
    float t1_0 = 0, t1_1 = 0, t1_2 = 0, t1_3 = 0;
    float t2_0 = 0, t2_1 = 0, t2_2 = 0, t2_3 = 0;

    for (int v = blockIdx.x * 16 + sub; v < N_NODES; v += gridDim.x * 16) {
        int e0 = row_ptr[v], e1 = row_ptr[v + 1];
        float a0 = 0, a1 = 0, a2 = 0, a3 = 0, b0 = 0, b1 = 0, b2 = 0, b3 = 0;
        for (int e = e0; e < e1; e += 16) {
            // one coalesced NT load per group covers 16 edges' metadata
            unsigned mo = (e + fl < e1) ? __builtin_nontemporal_load(em + e + fl) : 0u;
            unsigned mj[16];
            uint2 q[16];
#pragma unroll
            for (int j = 0; j < 16; j++) {
                mj[j] = (unsigned)__shfl((int)mo, srcbase + j, 64);
                q[j] = xw[(mj[j] >> 16) * 16 + fl];  // 8B gather: features 4fl..4fl+3
            }
#pragma unroll
            for (int j = 0; j < 16; j++) {
                float w = unpack_w(mj[j]);
                float2 f01 = unpack_x2(q[j].x);
                float2 f23 = unpack_x2(q[j].y);
                if (j & 1) {
                    b0 = fmaf(w, f01.x, b0); b1 = fmaf(w, f01.y, b1);
                    b2 = fmaf(w, f23.x, b2); b3 = fmaf(w, f23.y, b3);
                } else {
                    a0 = fmaf(w, f01.x, a0); a1 = fmaf(w, f01.y, a1);
                    a2 = fmaf(w, f23.x, a2); a3 = fmaf(w, f23.y, a3);
                }
            }
        }
        float h0 = a0 + b0 + bias.x;
        float h1 = a1 + b1 + bias.y;
        float h2 = a2 + b2 + bias.z;
        float h3 = a3 + b3 + bias.w;
        h0 = h0 >= 0.f ? h0 : al * h0;
        h1 = h1 >= 0.f ? h1 : al * h1;
        h2 = h2 >= 0.f ? h2 : al * h2;
        h3 = h3 >= 0.f ? h3 : al * h3;
        if (hraw_prev) {
            float2 p01 = ntload_f2((const float2*)hraw_prev + v * 32 + 2 * fl);
            float2 p23 = ntload_f2((const float2*)hraw_prev + v * 32 + 2 * fl + 1);
            h0 = fmaf(p01.x, sc0, h0 + sh0);
            h1 = fmaf(p01.y, sc1, h1 + sh1);
            h2 = fmaf(p23.x, sc2, h2 + sh2);
            h3 = fmaf(p23.y, sc3, h3 + sh3);
        }
        ntstore_f2((float2*)hpre + v * 32 + 2 * fl, make_float2(h0, h1));
        ntstore_f2((float2*)hpre + v * 32 + 2 * fl + 1, make_float2(h2, h3));
        t1_0 += h0; t1_1 += h1; t1_2 += h2; t1_3 += h3;
        t2_0 = fmaf(h0, h0, t2_0);
        t2_1 = fmaf(h1, h1, t2_1);
        t2_2 = fmaf(h2, h2, t2_2);
        t2_3 = fmaf(h3, h3, t2_3);
    }
    atomicAdd(&r1[c0 + 0], t1_0);
    atomicAdd(&r1[c0 + 1], t1_1);
    atomicAdd(&r1[c0 + 2], t1_2);
    atomicAdd(&r1[c0 + 3], t1_3);
    atomicAdd(&r2[c0 + 0], t2_0);
    atomicAdd(&r2[c0 + 1], t2_1);
    atomicAdd(&r2[c0 + 2], t2_2);
    atomicAdd(&r2[c0 + 3], t2_3);
    __syncthreads();
    if (tid < D) {
        atomicAdd(&bnsum[tid], r1[tid]);
        atomicAdd(&bnsum[D + tid], r2[tid]);
    }
}

// ---------------------------------------------------------------- final BN apply
__global__ __launch_bounds__(256) void bnapply_kernel(const float* __restrict__ hpre,
                                                      const float* __restrict__ bnsum_p,
                                                      const float* __restrict__ gamma_p,
                                                      const float* __restrict__ beta_p,
                                                      float* __restrict__ out) {
    __shared__ float aff[2][D];
    int tid = threadIdx.x;
    if (tid < D) {
        float sc, sh;
        bn_affine(bnsum_p, gamma_p, beta_p, tid, sc, sh);
        aff[0][tid] = sc;
        aff[1][tid] = sh;
    }
    __syncthreads();
    int i = blockIdx.x * blockDim.x + tid;
    int stride = gridDim.x * blockDim.x;
    const int NQ = N_NODES * D / 4;
    for (int j = i; j < NQ; j += stride) {
        float4 hv = ((const float4*)hpre)[j];
        int c = (j * 4) & 63;
        float4 o;
        o.x = fmaf(hv.x, aff[0][c + 0], aff[1][c + 0]);
        o.y = fmaf(hv.y, aff[0][c + 1], aff[1][c + 1]);
        o.z = fmaf(hv.z, aff[0][c + 2], aff[1][c + 2]);
        o.w = fmaf(hv.w, aff[0][c + 3], aff[1][c + 3]);
        ((float4*)out)[j] = o;
    }
}

// ---------------------------------------------------------------- launch
extern "C" void kernel_launch(void* const* d_in, const int* in_sizes, int n_in,
                              void* d_out, int out_size, void* d_ws, size_t ws_size,
                              hipStream_t stream) {
    const float* x     = (const float*)d_in[0];
    const int*   esrc  = (const int*)d_in[1];
    const int*   edst  = (const int*)d_in[2];
    const float* ew    = (const float*)d_in[3];
    const float* W     = (const float*)d_in[4];
    const float* b     = (const float*)d_in[5];
    const float* pa    = (const float*)d_in[6];
    const float* gamma = (const float*)d_in[7];
    const float* beta  = (const float*)d_in[8];
    float* out = (float*)d_out;

    char* ws = (char*)d_ws;
    size_t off = 0;
    auto alloc = [&](size_t bytes) -> char* {
        char* p = ws + off;
        off = (off + bytes + 255) & ~(size_t)255;
        return p;
    };
    int*            counts   = (int*)alloc((size_t)N_NODES * 4);
    int*            row_ptr  = (int*)alloc((size_t)(N_NODES + 1) * 4);
    int*            blocksum = (int*)alloc((size_t)NB_SCAN * 4);
    int*            blockoff = (int*)alloc((size_t)NB_SCAN * 4);
    unsigned short* rank     = (unsigned short*)alloc((size_t)N_EDGES * 2);
    unsigned int*   em       = (unsigned int*)alloc((size_t)N_EDGES * 4);
    __half*         xw       = (__half*)alloc((size_t)N_NODES * D * 2);
    float*          hpre1    = (float*)alloc((size_t)N_NODES * D * 4);
    float*          bnsum    = (float*)alloc((size_t)L * 2 * D * 4);

    init_kernel<<<256, 256, 0, stream>>>(counts, bnsum);
    count_kernel<<<2048, 256, 0, stream>>>(edst, counts, rank);
    scanA_kernel<<<NB_SCAN, 256, 0, stream>>>(counts, blocksum);
    scanB_kernel<<<1, 256, 0, stream>>>(blocksum, blockoff, row_ptr);
    scanC_kernel<<<NB_SCAN, 256, 0, stream>>>(counts, blockoff, row_ptr);
    fill_kernel<<<2048, 256, 0, stream>>>(esrc, edst, ew, rank, row_ptr, em);

    // hpre storage: layer0 -> d_out, layer1 -> ws, layer2 -> d_out
    float* hbuf[L] = {out, hpre1, out};
    for (int i = 0; i < L; i++) {
        const float* hin = (i == 0) ? x : hbuf[i - 1];
        const float* bns = (i == 0) ? nullptr : bnsum + (i - 1) * 2 * D;
        const float* gmp = (i == 0) ? nullptr : gamma + (i - 1) * D;
        const float* btp = (i == 0) ? nullptr : beta + (i - 1) * D;
        gemm_kernel<<<512, 256, 0, stream>>>(hin, bns, gmp, btp, W + (size_t)i * D * D, xw);
        agg_kernel<<<AGG_BLOCKS, 256, 0, stream>>>((const uint2*)xw, row_ptr, em,
                                                   b + i * D, pa + i,
                                                   (i == 0) ? nullptr : hbuf[i - 1],
                                                   bns, gmp, btp,
                                                   hbuf[i], bnsum + i * 2 * D);
    }
    bnapply_kernel<<<2048, 256, 0, stream>>>(hbuf[2], bnsum + 2 * 2 * D,
                                             gamma + 2 * D, beta + 2 * D, out);
}